// Round 2
// baseline (350.090 us; speedup 1.0000x reference)
//
#include <hip/hip_runtime.h>
#include <math.h>

#define NN 10000
#define BB 4
#define EE 160000
#define CC 64
#define CE 16

// ---- workspace layout (bytes) ----
static constexpr size_t OFF_XPA    = 0;
static constexpr size_t OFF_XPB    = 10240000;
static constexpr size_t OFF_SA     = 20480000;
static constexpr size_t OFF_SB     = 20640000;
static constexpr size_t OFF_VECS   = 20800000;
static constexpr size_t OFF_COUNTS = 20801280;
static constexpr size_t OFF_CURSOR = 20841280;
static constexpr size_t OFF_OFFS   = 20881280;
static constexpr size_t OFF_RECS   = 20921344;

__device__ __forceinline__ float sigmoidf_(float x) {
    return 1.0f / (1.0f + __expf(-x));
}

// zero counts+cursor (2*NN ints, contiguous)
__global__ void zero_kernel(int* p, int n) {
    int i = blockIdx.x * blockDim.x + threadIdx.x;
    if (i < n) p[i] = 0;
}

__global__ void hist_kernel(const int* __restrict__ ei, int* __restrict__ counts) {
    int e = blockIdx.x * blockDim.x + threadIdx.x;
    if (e < EE) atomicAdd(&counts[ei[EE + e]], 1);
}

// single-block exclusive scan of counts[0..n) -> offs[0..n]
__global__ void scan_kernel(const int* __restrict__ counts, int* __restrict__ offs, int n) {
    __shared__ int sm[1024];
    __shared__ int carry_s;
    int t = threadIdx.x;
    if (t == 0) carry_s = 0;
    __syncthreads();
    for (int base = 0; base < n; base += 1024) {
        int i = base + t;
        int v = (i < n) ? counts[i] : 0;
        sm[t] = v;
        __syncthreads();
        for (int off = 1; off < 1024; off <<= 1) {
            int add = (t >= off) ? sm[t - off] : 0;
            __syncthreads();
            sm[t] += add;
            __syncthreads();
        }
        int carry = carry_s;
        if (i < n) offs[i] = carry + sm[t] - v;
        __syncthreads();
        if (t == 1023) carry_s = carry + sm[1023];
        __syncthreads();
    }
    if (t == 0) offs[n] = carry_s;
}

__global__ void scatter_kernel(const int* __restrict__ ei, const int* __restrict__ offs,
                               int* __restrict__ cursor, int2* __restrict__ recs) {
    int e = blockIdx.x * blockDim.x + threadIdx.x;
    if (e >= EE) return;
    int s = ei[e], d = ei[EE + e];
    int p = atomicAdd(&cursor[d], 1);
    recs[offs[d] + p] = make_int2(s, e);
}

// fold q@aw_q, k@aw_k (64-vecs) and w_e@aw_e (16-vec) for both layers
__global__ void vecs_kernel(const float* __restrict__ q1, const float* __restrict__ k1,
                            const float* __restrict__ aw1, const float* __restrict__ we1,
                            const float* __restrict__ q2, const float* __restrict__ k2,
                            const float* __restrict__ aw2, const float* __restrict__ we2,
                            float* __restrict__ vecs) {
    int t = threadIdx.x;
    if (t < 64) {
        float a = 0.f, b = 0.f, c = 0.f, d = 0.f;
        for (int j = 0; j < 64; ++j) {
            a = fmaf(q1[t * 64 + j], aw1[j], a);
            b = fmaf(k1[t * 64 + j], aw1[64 + j], b);
            c = fmaf(q2[t * 64 + j], aw2[j], c);
            d = fmaf(k2[t * 64 + j], aw2[64 + j], d);
        }
        vecs[t] = a; vecs[64 + t] = b; vecs[144 + t] = c; vecs[208 + t] = d;
    }
    if (t < 16) {
        float a = 0.f, b = 0.f;
        for (int j = 0; j < 64; ++j) {
            a = fmaf(we1[t * 64 + j], aw1[128 + j], a);
            b = fmaf(we2[t * 64 + j], aw2[128 + j], b);
        }
        vecs[128 + t] = a; vecs[272 + t] = b;
    }
}

// xp = x @ w_n ; sa = xp@qa ; sb = xp@ka.  One wave per node, 4 nodes/block.
__global__ __launch_bounds__(256) void node_prep_kernel(
    const float* __restrict__ x,   // [NN,BB,CC]
    const float* __restrict__ w_n, // [CC,CC]
    const float* __restrict__ qa,  // [64]
    const float* __restrict__ ka,  // [64]
    float* __restrict__ xp,        // [NN,BB,CC]
    float* __restrict__ sa,        // [NN,BB]
    float* __restrict__ sb) {
    __shared__ float w_sh[64 * 64];     // 16 KB
    __shared__ float x_sh[4 * BB * CC]; // 4 KB
    int t = threadIdx.x;
    for (int i = t; i < 64 * 64; i += 256) w_sh[i] = w_n[i];
    int node0 = blockIdx.x * 4;
    const float4* xg = (const float4*)(x + (size_t)node0 * BB * CC);
    ((float4*)x_sh)[t] = xg[t];
    __syncthreads();
    int wave = t >> 6, lane = t & 63;
    int node = node0 + wave;
    const float* xrow = x_sh + wave * BB * CC;
    float acc0 = 0.f, acc1 = 0.f, acc2 = 0.f, acc3 = 0.f;
    #pragma unroll 8
    for (int ci = 0; ci < 64; ++ci) {
        float w = w_sh[ci * 64 + lane];
        acc0 = fmaf(xrow[ci], w, acc0);
        acc1 = fmaf(xrow[64 + ci], w, acc1);
        acc2 = fmaf(xrow[128 + ci], w, acc2);
        acc3 = fmaf(xrow[192 + ci], w, acc3);
    }
    size_t obase = (size_t)node * BB * CC + lane;
    xp[obase] = acc0;
    xp[obase + 64] = acc1;
    xp[obase + 128] = acc2;
    xp[obase + 192] = acc3;
    float qv = qa[lane], kv = ka[lane];
    float ra0 = acc0 * qv, ra1 = acc1 * qv, ra2 = acc2 * qv, ra3 = acc3 * qv;
    float rb0 = acc0 * kv, rb1 = acc1 * kv, rb2 = acc2 * kv, rb3 = acc3 * kv;
    #pragma unroll
    for (int off = 32; off >= 1; off >>= 1) {
        ra0 += __shfl_xor(ra0, off, 64); ra1 += __shfl_xor(ra1, off, 64);
        ra2 += __shfl_xor(ra2, off, 64); ra3 += __shfl_xor(ra3, off, 64);
        rb0 += __shfl_xor(rb0, off, 64); rb1 += __shfl_xor(rb1, off, 64);
        rb2 += __shfl_xor(rb2, off, 64); rb3 += __shfl_xor(rb3, off, 64);
    }
    if (lane == 0) {
        sa[node * BB + 0] = ra0; sa[node * BB + 1] = ra1;
        sa[node * BB + 2] = ra2; sa[node * BB + 3] = ra3;
        sb[node * BB + 0] = rb0; sb[node * BB + 1] = rb1;
        sb[node * BB + 2] = rb2; sb[node * BB + 3] = rb3;
    }
}

// Per-node segment-max aggregation + output linear + residual + leaky_relu.
// One wave per node (lane = channel), 4 nodes per block.
__global__ __launch_bounds__(256) void conv_out_kernel(
    const float* __restrict__ xp,      // [NN,BB,CC]
    const float* __restrict__ sa,      // [NN,BB]
    const float* __restrict__ sb,      // [NN,BB]
    const int2* __restrict__ recs,     // [EE] {src, e}
    const int* __restrict__ offs,      // [NN+1]
    const float* __restrict__ attr,    // [EE,CE]
    const float* __restrict__ w_e,     // [CE,CC]
    const float* __restrict__ wea,     // [CE]
    const float* __restrict__ ab,      // [1]
    const float* __restrict__ ow,      // [2*CC,CC]
    const float* __restrict__ ob,      // [CC]
    float* __restrict__ out) {         // [NN,BB,CC]
    __shared__ float ow_sh[128 * 64];        // 32 KB
    __shared__ float aggr_sh[4][BB][CC];     // 4 KB
    __shared__ float xpn_sh[4][BB][CC];      // 4 KB
    int t = threadIdx.x;
    for (int i = t; i < 128 * 64; i += 256) ow_sh[i] = ow[i];
    int wave = t >> 6, lane = t & 63;
    int node = blockIdx.x * 4 + wave;

    float wec[CE], weav[CE];
    #pragma unroll
    for (int j = 0; j < CE; ++j) {
        wec[j] = w_e[j * CC + lane];
        weav[j] = wea[j];
    }
    float abv = ab[0];
    float4 sbn = *(const float4*)(sb + node * BB);
    int o0 = offs[node], o1 = offs[node + 1];

    float m0 = -INFINITY, m1 = -INFINITY, m2 = -INFINITY, m3 = -INFINITY;
    for (int i = o0; i < o1; ++i) {
        int2 rec = recs[i];
        int s = rec.x, e = rec.y;
        const float4* ap = (const float4*)(attr + (size_t)e * CE);
        float4 a0 = ap[0], a1 = ap[1], a2 = ap[2], a3 = ap[3];
        float av[16] = {a0.x, a0.y, a0.z, a0.w, a1.x, a1.y, a1.z, a1.w,
                        a2.x, a2.y, a2.z, a2.w, a3.x, a3.y, a3.z, a3.w};
        float g = 0.f, se = 0.f;
        #pragma unroll
        for (int j = 0; j < CE; ++j) {
            g = fmaf(av[j], wec[j], g);
            se = fmaf(av[j], weav[j], se);
        }
        g = sigmoidf_(g);
        float4 sas = *(const float4*)(sa + s * BB);
        const float* xs = xp + (size_t)s * BB * CC + lane;
        float x0 = xs[0], x1 = xs[64], x2 = xs[128], x3 = xs[192];
        float at0 = sigmoidf_(sas.x + sbn.x + se + abv);
        float at1 = sigmoidf_(sas.y + sbn.y + se + abv);
        float at2 = sigmoidf_(sas.z + sbn.z + se + abv);
        float at3 = sigmoidf_(sas.w + sbn.w + se + abv);
        m0 = fmaxf(m0, at0 * x0 * g);
        m1 = fmaxf(m1, at1 * x1 * g);
        m2 = fmaxf(m2, at2 * x2 * g);
        m3 = fmaxf(m3, at3 * x3 * g);
    }
    // empty segments -> 0
    m0 = (m0 == -INFINITY) ? 0.f : m0;
    m1 = (m1 == -INFINITY) ? 0.f : m1;
    m2 = (m2 == -INFINITY) ? 0.f : m2;
    m3 = (m3 == -INFINITY) ? 0.f : m3;

    const float* xn = xp + (size_t)node * BB * CC + lane;
    float xn0 = xn[0], xn1 = xn[64], xn2 = xn[128], xn3 = xn[192];
    aggr_sh[wave][0][lane] = m0; aggr_sh[wave][1][lane] = m1;
    aggr_sh[wave][2][lane] = m2; aggr_sh[wave][3][lane] = m3;
    xpn_sh[wave][0][lane] = xn0; xpn_sh[wave][1][lane] = xn1;
    xpn_sh[wave][2][lane] = xn2; xpn_sh[wave][3][lane] = xn3;
    __syncthreads();

    float o0f = 0.f, o1f = 0.f, o2f = 0.f, o3f = 0.f;
    #pragma unroll 4
    for (int ci = 0; ci < 64; ++ci) {
        float wa = ow_sh[ci * 64 + lane];
        float wb = ow_sh[(64 + ci) * 64 + lane];
        o0f = fmaf(xpn_sh[wave][0][ci], wa, o0f);
        o1f = fmaf(xpn_sh[wave][1][ci], wa, o1f);
        o2f = fmaf(xpn_sh[wave][2][ci], wa, o2f);
        o3f = fmaf(xpn_sh[wave][3][ci], wa, o3f);
        o0f = fmaf(aggr_sh[wave][0][ci], wb, o0f);
        o1f = fmaf(aggr_sh[wave][1][ci], wb, o1f);
        o2f = fmaf(aggr_sh[wave][2][ci], wb, o2f);
        o3f = fmaf(aggr_sh[wave][3][ci], wb, o3f);
    }
    // out = xp + (concat([xp, aggr]) @ ow + ob), then leaky_relu(0.01)
    float obv = ob[lane];
    float r0 = xn0 + o0f + obv;
    float r1 = xn1 + o1f + obv;
    float r2 = xn2 + o2f + obv;
    float r3 = xn3 + o3f + obv;
    r0 = (r0 > 0.f) ? r0 : 0.01f * r0;
    r1 = (r1 > 0.f) ? r1 : 0.01f * r1;
    r2 = (r2 > 0.f) ? r2 : 0.01f * r2;
    r3 = (r3 > 0.f) ? r3 : 0.01f * r3;
    float* op = out + (size_t)node * BB * CC + lane;
    op[0] = r0; op[64] = r1; op[128] = r2; op[192] = r3;
}

extern "C" void kernel_launch(void* const* d_in, const int* in_sizes, int n_in,
                              void* d_out, int out_size, void* d_ws, size_t ws_size,
                              hipStream_t stream) {
    const float* X    = (const float*)d_in[0];
    const int*   ei   = (const int*)d_in[1];
    const float* attr = (const float*)d_in[2];
    const float* w_n1 = (const float*)d_in[3];
    const float* w_e1 = (const float*)d_in[4];
    const float* q1   = (const float*)d_in[5];
    const float* k1   = (const float*)d_in[6];
    const float* aw1  = (const float*)d_in[7];
    const float* ab1  = (const float*)d_in[8];
    const float* ow1  = (const float*)d_in[9];
    const float* ob1  = (const float*)d_in[10];
    const float* w_n2 = (const float*)d_in[11];
    const float* w_e2 = (const float*)d_in[12];
    const float* q2   = (const float*)d_in[13];
    const float* k2   = (const float*)d_in[14];
    const float* aw2  = (const float*)d_in[15];
    const float* ab2  = (const float*)d_in[16];
    const float* ow2  = (const float*)d_in[17];
    const float* ob2  = (const float*)d_in[18];
    float* out = (float*)d_out;

    char* ws = (char*)d_ws;
    float* xpA    = (float*)(ws + OFF_XPA);
    float* xpB    = (float*)(ws + OFF_XPB);
    float* sa     = (float*)(ws + OFF_SA);
    float* sb     = (float*)(ws + OFF_SB);
    float* vecs   = (float*)(ws + OFF_VECS);
    int*   counts = (int*)(ws + OFF_COUNTS);
    int*   cursor = (int*)(ws + OFF_CURSOR);
    int*   offs   = (int*)(ws + OFF_OFFS);
    int2*  recs   = (int2*)(ws + OFF_RECS);

    // CSR build (edge_index is layer-invariant)
    zero_kernel<<<(2 * NN + 255) / 256, 256, 0, stream>>>(counts, 2 * NN); // counts+cursor
    hist_kernel<<<EE / 256, 256, 0, stream>>>(ei, counts);
    scan_kernel<<<1, 1024, 0, stream>>>(counts, offs, NN);
    scatter_kernel<<<EE / 256, 256, 0, stream>>>(ei, offs, cursor, recs);
    vecs_kernel<<<1, 256, 0, stream>>>(q1, k1, aw1, w_e1, q2, k2, aw2, w_e2, vecs);

    // layer 1
    node_prep_kernel<<<NN / 4, 256, 0, stream>>>(X, w_n1, vecs + 0, vecs + 64, xpA, sa, sb);
    conv_out_kernel<<<NN / 4, 256, 0, stream>>>(xpA, sa, sb, recs, offs, attr, w_e1,
                                                vecs + 128, ab1, ow1, ob1, xpB);
    // layer 2
    node_prep_kernel<<<NN / 4, 256, 0, stream>>>(xpB, w_n2, vecs + 144, vecs + 208, xpA, sa, sb);
    conv_out_kernel<<<NN / 4, 256, 0, stream>>>(xpA, sa, sb, recs, offs, attr, w_e2,
                                                vecs + 272, ab2, ow2, ob2, out);
}

// Round 3
// 312.835 us; speedup vs baseline: 1.1191x; 1.1191x over previous
//
#include <hip/hip_runtime.h>
#include <math.h>

#define NN 10000
#define BB 4
#define EE 160000
#define CC 64
#define CE 16

// ---- workspace layout (bytes) ----
static constexpr size_t OFF_XPA    = 0;          // float[NN*BB*CC]
static constexpr size_t OFF_XPB    = 10240000;   // float[NN*BB*CC]
static constexpr size_t OFF_SA     = 20480000;   // float[NN*BB]
static constexpr size_t OFF_SB     = 20640000;   // float[NN*BB]
static constexpr size_t OFF_VECS   = 20800000;   // float[288]
static constexpr size_t OFF_COUNTS = 20801280;   // int[NN]
static constexpr size_t OFF_CURSOR = 20841280;   // int[NN]
static constexpr size_t OFF_OFFS   = 20881280;   // int[NN+1]
static constexpr size_t OFF_RECS   = 20921344;   // int2[EE]
static constexpr size_t OFF_ATT    = 22201344;   // float4[EE]  (2.56 MB) -> total ~24.8 MB

__device__ __forceinline__ float sigmoidf_(float x) {
    return 1.0f / (1.0f + __expf(-x));
}

// histogram of dst + (block 0) fold q@aw_q, k@aw_k, w_e@aw_e for both layers
__global__ void hist_vecs_kernel(const int* __restrict__ ei, int* __restrict__ counts,
                                 const float* __restrict__ q1, const float* __restrict__ k1,
                                 const float* __restrict__ aw1, const float* __restrict__ we1,
                                 const float* __restrict__ q2, const float* __restrict__ k2,
                                 const float* __restrict__ aw2, const float* __restrict__ we2,
                                 float* __restrict__ vecs) {
    int e = blockIdx.x * blockDim.x + threadIdx.x;
    if (e < EE) atomicAdd(&counts[ei[EE + e]], 1);
    if (blockIdx.x == 0) {
        int t = threadIdx.x;
        if (t < 64) {
            float a = 0.f, b = 0.f, c = 0.f, d = 0.f;
            for (int j = 0; j < 64; ++j) {
                a = fmaf(q1[t * 64 + j], aw1[j], a);
                b = fmaf(k1[t * 64 + j], aw1[64 + j], b);
                c = fmaf(q2[t * 64 + j], aw2[j], c);
                d = fmaf(k2[t * 64 + j], aw2[64 + j], d);
            }
            vecs[t] = a; vecs[64 + t] = b; vecs[144 + t] = c; vecs[208 + t] = d;
        }
        if (t < 16) {
            float a = 0.f, b = 0.f;
            for (int j = 0; j < 64; ++j) {
                a = fmaf(we1[t * 64 + j], aw1[128 + j], a);
                b = fmaf(we2[t * 64 + j], aw2[128 + j], b);
            }
            vecs[128 + t] = a; vecs[272 + t] = b;
        }
    }
}

// single-block exclusive scan of counts[0..n) -> offs[0..n]
__global__ void scan_kernel(const int* __restrict__ counts, int* __restrict__ offs, int n) {
    __shared__ int sm[1024];
    __shared__ int carry_s;
    int t = threadIdx.x;
    if (t == 0) carry_s = 0;
    __syncthreads();
    for (int base = 0; base < n; base += 1024) {
        int i = base + t;
        int v = (i < n) ? counts[i] : 0;
        sm[t] = v;
        __syncthreads();
        for (int off = 1; off < 1024; off <<= 1) {
            int add = (t >= off) ? sm[t - off] : 0;
            __syncthreads();
            sm[t] += add;
            __syncthreads();
        }
        int carry = carry_s;
        if (i < n) offs[i] = carry + sm[t] - v;
        __syncthreads();
        if (t == 1023) carry_s = carry + sm[1023];
        __syncthreads();
    }
    if (t == 0) offs[n] = carry_s;
}

__global__ void scatter_kernel(const int* __restrict__ ei, const int* __restrict__ offs,
                               int* __restrict__ cursor, int2* __restrict__ recs) {
    int e = blockIdx.x * blockDim.x + threadIdx.x;
    if (e >= EE) return;
    int s = ei[e], d = ei[EE + e];
    int p = atomicAdd(&cursor[d], 1);
    recs[offs[d] + p] = make_int2(s, e);
}

// xp = x @ w_n ; sa = xp@qa ; sb = xp@ka.  One wave per node, 4 nodes/block.
__global__ __launch_bounds__(256) void node_prep_kernel(
    const float* __restrict__ x,   // [NN,BB,CC]
    const float* __restrict__ w_n, // [CC,CC]
    const float* __restrict__ qa,  // [64]
    const float* __restrict__ ka,  // [64]
    float* __restrict__ xp,        // [NN,BB,CC]
    float* __restrict__ sa,        // [NN,BB]
    float* __restrict__ sb) {
    __shared__ float w_sh[64 * 64];     // 16 KB
    __shared__ float x_sh[4 * BB * CC]; // 4 KB
    int t = threadIdx.x;
    for (int i = t; i < 64 * 64; i += 256) w_sh[i] = w_n[i];
    int node0 = blockIdx.x * 4;
    const float4* xg = (const float4*)(x + (size_t)node0 * BB * CC);
    ((float4*)x_sh)[t] = xg[t];
    __syncthreads();
    int wave = t >> 6, lane = t & 63;
    int node = node0 + wave;
    const float* xrow = x_sh + wave * BB * CC;
    float acc0 = 0.f, acc1 = 0.f, acc2 = 0.f, acc3 = 0.f;
    #pragma unroll 8
    for (int ci = 0; ci < 64; ++ci) {
        float w = w_sh[ci * 64 + lane];
        acc0 = fmaf(xrow[ci], w, acc0);
        acc1 = fmaf(xrow[64 + ci], w, acc1);
        acc2 = fmaf(xrow[128 + ci], w, acc2);
        acc3 = fmaf(xrow[192 + ci], w, acc3);
    }
    size_t obase = (size_t)node * BB * CC + lane;
    xp[obase] = acc0;
    xp[obase + 64] = acc1;
    xp[obase + 128] = acc2;
    xp[obase + 192] = acc3;
    float qv = qa[lane], kv = ka[lane];
    float ra0 = acc0 * qv, ra1 = acc1 * qv, ra2 = acc2 * qv, ra3 = acc3 * qv;
    float rb0 = acc0 * kv, rb1 = acc1 * kv, rb2 = acc2 * kv, rb3 = acc3 * kv;
    #pragma unroll
    for (int off = 32; off >= 1; off >>= 1) {
        ra0 += __shfl_xor(ra0, off, 64); ra1 += __shfl_xor(ra1, off, 64);
        ra2 += __shfl_xor(ra2, off, 64); ra3 += __shfl_xor(ra3, off, 64);
        rb0 += __shfl_xor(rb0, off, 64); rb1 += __shfl_xor(rb1, off, 64);
        rb2 += __shfl_xor(rb2, off, 64); rb3 += __shfl_xor(rb3, off, 64);
    }
    if (lane == 0) {
        sa[node * BB + 0] = ra0; sa[node * BB + 1] = ra1;
        sa[node * BB + 2] = ra2; sa[node * BB + 3] = ra3;
        sb[node * BB + 0] = rb0; sb[node * BB + 1] = rb1;
        sb[node * BB + 2] = rb2; sb[node * BB + 3] = rb3;
    }
}

// per-edge attention scalar: att4[e] = sigmoid(sa[src] + sb[dst] + attr[e]·weav + ab)
__global__ __launch_bounds__(256) void att_kernel(
    const int* __restrict__ ei, const float* __restrict__ attr,
    const float* __restrict__ sa, const float* __restrict__ sb,
    const float* __restrict__ weav,  // [16] (uniform)
    const float* __restrict__ ab,    // [1]
    float4* __restrict__ att) {
    int e = blockIdx.x * blockDim.x + threadIdx.x;
    if (e >= EE) return;
    int s = ei[e], d = ei[EE + e];
    const float4* ap = (const float4*)(attr + (size_t)e * CE);
    float4 a0 = ap[0], a1 = ap[1], a2 = ap[2], a3 = ap[3];
    float se = ab[0];
    se = fmaf(a0.x, weav[0], se);  se = fmaf(a0.y, weav[1], se);
    se = fmaf(a0.z, weav[2], se);  se = fmaf(a0.w, weav[3], se);
    se = fmaf(a1.x, weav[4], se);  se = fmaf(a1.y, weav[5], se);
    se = fmaf(a1.z, weav[6], se);  se = fmaf(a1.w, weav[7], se);
    se = fmaf(a2.x, weav[8], se);  se = fmaf(a2.y, weav[9], se);
    se = fmaf(a2.z, weav[10], se); se = fmaf(a2.w, weav[11], se);
    se = fmaf(a3.x, weav[12], se); se = fmaf(a3.y, weav[13], se);
    se = fmaf(a3.z, weav[14], se); se = fmaf(a3.w, weav[15], se);
    float4 sas = *(const float4*)(sa + (size_t)s * BB);
    float4 sbn = *(const float4*)(sb + (size_t)d * BB);
    float4 r;
    r.x = sigmoidf_(sas.x + sbn.x + se);
    r.y = sigmoidf_(sas.y + sbn.y + se);
    r.z = sigmoidf_(sas.z + sbn.z + se);
    r.w = sigmoidf_(sas.w + sbn.w + se);
    att[e] = r;
}

// Per-node segment-max aggregation + output linear + residual + leaky_relu.
// One wave per node (lane = channel), 4 nodes per block. LDS = 8 KB only.
__global__ __launch_bounds__(256) void conv_out_kernel(
    const float* __restrict__ xp,      // [NN,BB,CC]
    const int2* __restrict__ recs,     // [EE] {src, e}
    const int* __restrict__ offs,      // [NN+1]
    const float* __restrict__ attr,    // [EE,CE]
    const float* __restrict__ w_e,     // [CE,CC]
    const float4* __restrict__ att,    // [EE]
    const float* __restrict__ ow,      // [2*CC,CC]
    const float* __restrict__ ob,      // [CC]
    float* __restrict__ out) {         // [NN,BB,CC]
    __shared__ float aggr_sh[4][BB * CC];  // 4 KB
    __shared__ float xpn_sh[4][BB * CC];   // 4 KB
    int t = threadIdx.x;
    int wave = t >> 6, lane = t & 63;
    int node = blockIdx.x * 4 + wave;

    float wec[CE];
    #pragma unroll
    for (int j = 0; j < CE; ++j) wec[j] = w_e[j * CC + lane];

    // own-node xp rows (independent of the edge loop; load early)
    const float* xn = xp + (size_t)node * BB * CC + lane;
    float xn0 = xn[0], xn1 = xn[64], xn2 = xn[128], xn3 = xn[192];

    int o0 = offs[node], o1 = offs[node + 1];
    float m0 = -INFINITY, m1 = -INFINITY, m2 = -INFINITY, m3 = -INFINITY;

    int i = o0;
    int2 rec = (i < o1) ? recs[i] : make_int2(0, 0);
    while (i < o1) {
        int2 cur = rec;
        ++i;
        if (i < o1) rec = recs[i];  // prefetch next
        int s = cur.x, e = cur.y;
        float4 at = att[e];
        const float4* ap = (const float4*)(attr + (size_t)e * CE);
        float4 a0 = ap[0], a1 = ap[1], a2 = ap[2], a3 = ap[3];
        float g = 0.f;
        g = fmaf(a0.x, wec[0], g);  g = fmaf(a0.y, wec[1], g);
        g = fmaf(a0.z, wec[2], g);  g = fmaf(a0.w, wec[3], g);
        g = fmaf(a1.x, wec[4], g);  g = fmaf(a1.y, wec[5], g);
        g = fmaf(a1.z, wec[6], g);  g = fmaf(a1.w, wec[7], g);
        g = fmaf(a2.x, wec[8], g);  g = fmaf(a2.y, wec[9], g);
        g = fmaf(a2.z, wec[10], g); g = fmaf(a2.w, wec[11], g);
        g = fmaf(a3.x, wec[12], g); g = fmaf(a3.y, wec[13], g);
        g = fmaf(a3.z, wec[14], g); g = fmaf(a3.w, wec[15], g);
        g = sigmoidf_(g);
        const float* xs = xp + (size_t)s * BB * CC + lane;
        float x0 = xs[0], x1 = xs[64], x2 = xs[128], x3 = xs[192];
        m0 = fmaxf(m0, at.x * x0 * g);
        m1 = fmaxf(m1, at.y * x1 * g);
        m2 = fmaxf(m2, at.z * x2 * g);
        m3 = fmaxf(m3, at.w * x3 * g);
    }
    // empty segments -> 0
    m0 = (m0 == -INFINITY) ? 0.f : m0;
    m1 = (m1 == -INFINITY) ? 0.f : m1;
    m2 = (m2 == -INFINITY) ? 0.f : m2;
    m3 = (m3 == -INFINITY) ? 0.f : m3;

    aggr_sh[wave][0 * CC + lane] = m0; aggr_sh[wave][1 * CC + lane] = m1;
    aggr_sh[wave][2 * CC + lane] = m2; aggr_sh[wave][3 * CC + lane] = m3;
    xpn_sh[wave][0 * CC + lane] = xn0; xpn_sh[wave][1 * CC + lane] = xn1;
    xpn_sh[wave][2 * CC + lane] = xn2; xpn_sh[wave][3 * CC + lane] = xn3;
    __syncthreads();

    const float* xr = xpn_sh[wave];
    const float* ar = aggr_sh[wave];
    float o0f = 0.f, o1f = 0.f, o2f = 0.f, o3f = 0.f;
    #pragma unroll 4
    for (int ci = 0; ci < 64; ++ci) {
        float wa = ow[ci * 64 + lane];         // L2-resident, same 32 KB per block
        float wb = ow[(64 + ci) * 64 + lane];
        o0f = fmaf(xr[ci], wa, o0f);
        o1f = fmaf(xr[CC + ci], wa, o1f);
        o2f = fmaf(xr[2 * CC + ci], wa, o2f);
        o3f = fmaf(xr[3 * CC + ci], wa, o3f);
        o0f = fmaf(ar[ci], wb, o0f);
        o1f = fmaf(ar[CC + ci], wb, o1f);
        o2f = fmaf(ar[2 * CC + ci], wb, o2f);
        o3f = fmaf(ar[3 * CC + ci], wb, o3f);
    }
    // out = xp + (concat([xp, aggr]) @ ow + ob), then leaky_relu(0.01)
    float obv = ob[lane];
    float r0 = xn0 + o0f + obv;
    float r1 = xn1 + o1f + obv;
    float r2 = xn2 + o2f + obv;
    float r3 = xn3 + o3f + obv;
    r0 = (r0 > 0.f) ? r0 : 0.01f * r0;
    r1 = (r1 > 0.f) ? r1 : 0.01f * r1;
    r2 = (r2 > 0.f) ? r2 : 0.01f * r2;
    r3 = (r3 > 0.f) ? r3 : 0.01f * r3;
    float* op = out + (size_t)node * BB * CC + lane;
    op[0] = r0; op[64] = r1; op[128] = r2; op[192] = r3;
}

extern "C" void kernel_launch(void* const* d_in, const int* in_sizes, int n_in,
                              void* d_out, int out_size, void* d_ws, size_t ws_size,
                              hipStream_t stream) {
    const float* X    = (const float*)d_in[0];
    const int*   ei   = (const int*)d_in[1];
    const float* attr = (const float*)d_in[2];
    const float* w_n1 = (const float*)d_in[3];
    const float* w_e1 = (const float*)d_in[4];
    const float* q1   = (const float*)d_in[5];
    const float* k1   = (const float*)d_in[6];
    const float* aw1  = (const float*)d_in[7];
    const float* ab1  = (const float*)d_in[8];
    const float* ow1  = (const float*)d_in[9];
    const float* ob1  = (const float*)d_in[10];
    const float* w_n2 = (const float*)d_in[11];
    const float* w_e2 = (const float*)d_in[12];
    const float* q2   = (const float*)d_in[13];
    const float* k2   = (const float*)d_in[14];
    const float* aw2  = (const float*)d_in[15];
    const float* ab2  = (const float*)d_in[16];
    const float* ow2  = (const float*)d_in[17];
    const float* ob2  = (const float*)d_in[18];
    float* out = (float*)d_out;

    char* ws = (char*)d_ws;
    float*  xpA    = (float*)(ws + OFF_XPA);
    float*  xpB    = (float*)(ws + OFF_XPB);
    float*  sa     = (float*)(ws + OFF_SA);
    float*  sb     = (float*)(ws + OFF_SB);
    float*  vecs   = (float*)(ws + OFF_VECS);
    int*    counts = (int*)(ws + OFF_COUNTS);
    int*    cursor = (int*)(ws + OFF_CURSOR);
    int*    offs   = (int*)(ws + OFF_OFFS);
    int2*   recs   = (int2*)(ws + OFF_RECS);
    float4* att    = (float4*)(ws + OFF_ATT);

    // CSR build (edge_index is layer-invariant)
    hipMemsetAsync(counts, 0, 2 * NN * sizeof(int), stream);  // counts + cursor
    hist_vecs_kernel<<<EE / 256, 256, 0, stream>>>(ei, counts, q1, k1, aw1, w_e1,
                                                   q2, k2, aw2, w_e2, vecs);
    scan_kernel<<<1, 1024, 0, stream>>>(counts, offs, NN);
    scatter_kernel<<<EE / 256, 256, 0, stream>>>(ei, offs, cursor, recs);

    // layer 1
    node_prep_kernel<<<NN / 4, 256, 0, stream>>>(X, w_n1, vecs + 0, vecs + 64, xpA, sa, sb);
    att_kernel<<<EE / 256, 256, 0, stream>>>(ei, attr, sa, sb, vecs + 128, ab1, att);
    conv_out_kernel<<<NN / 4, 256, 0, stream>>>(xpA, recs, offs, attr, w_e1, att,
                                                ow1, ob1, xpB);
    // layer 2
    node_prep_kernel<<<NN / 4, 256, 0, stream>>>(xpB, w_n2, vecs + 144, vecs + 208, xpA, sa, sb);
    att_kernel<<<EE / 256, 256, 0, stream>>>(ei, attr, sa, sb, vecs + 272, ab2, att);
    conv_out_kernel<<<NN / 4, 256, 0, stream>>>(xpA, recs, offs, attr, w_e2, att,
                                                ow2, ob2, out);
}